// Round 8
// baseline (508.920 us; speedup 1.0000x reference)
//
#include <hip/hip_runtime.h>
#include <hip/hip_bf16.h>

typedef __attribute__((ext_vector_type(8))) short bf16x8;
typedef __attribute__((ext_vector_type(4))) float f32x4;

#define CAP 64   // fixed per-node edge slot capacity (deg>CAP -> exact fallback)
#define SH  8    // shards (== XCD count; blockIdx%8 ~ XCD heuristic)

// fp32 -> bf16 (round-to-nearest-even), bit pattern as ushort
static __device__ inline unsigned short f2b(float f) {
    unsigned u = __float_as_uint(f);
    unsigned r = (u + 0x7FFFu + ((u >> 16) & 1u)) >> 16;
    return (unsigned short)r;
}
// packed bf16 pair -> two fp32
static __device__ inline float blo(unsigned u) { return __uint_as_float(u << 16); }
static __device__ inline float bhi(unsigned u) { return __uint_as_float(u & 0xFFFF0000u); }

// ---------------------------------------------------------------------------
__global__ void zero_kernel(int* __restrict__ p, int n) {
    int i = blockIdx.x * blockDim.x + threadIdx.x;
    if (i < n) p[i] = 0;
}

// ---------------------------------------------------------------------------
// XCD-sharded slot fill. Shard s owns dst in [s*npg, (s+1)*npg); block b
// serves shard b&7 (lands on XCD b&7 -> each node's 128B slot line dirtied by
// one XCD -> single writeback). After this kernel cursor[d] == in-degree(d).
// edge_index int32: row 0 = src (ei[0..E)), row 1 = dst (ei[E..2E)).
// ---------------------------------------------------------------------------
__global__ __launch_bounds__(256) void fill_shard_kernel(
        const int* __restrict__ ei, int* __restrict__ cursor,
        unsigned short* __restrict__ edge16, int E, int N, int G, int npg) {
    int s = blockIdx.x & (SH - 1);
    int i = blockIdx.x >> 3;
    int d_lo = s * npg;
    int d_hi = d_lo + npg; if (d_hi > N) d_hi = N;
    int C = (E + G - 1) / G;
    int e0 = i * C;
    int e1 = e0 + C; if (e1 > E) e1 = E;
    for (int e = e0 + threadIdx.x; e < e1; e += 256) {
        int d = ei[E + e];
        if (d < d_lo || d >= d_hi) continue;
        int src = ei[e];
        if ((unsigned)src >= (unsigned)N) src = 0;   // defensive
        int pos = atomicAdd(&cursor[d], 1);
        if (pos < CAP) edge16[(size_t)d * CAP + pos] = (unsigned short)src;
    }
}

// ---------------------------------------------------------------------------
// Merged conversions (one launch):
// blocks [0, G1): x fp32 -> xb bf16 (float4 -> ushort4 per thread)
// blocks [G1, G1+256): weights -> wt[layer][n][k] bf16 (k<128: Wl[k][n],
//   k>=128: Wr[k-128][n]); 2*128*256 = 65536 elems = 256 blocks x 256 thr.
// ---------------------------------------------------------------------------
__global__ __launch_bounds__(256) void convert_kernel(
        const float* __restrict__ x, unsigned short* __restrict__ xb, int n4,
        const float* __restrict__ W1l, const float* __restrict__ W1r,
        const float* __restrict__ W2l, const float* __restrict__ W2r,
        unsigned short* __restrict__ wt, int G1) {
    int b = blockIdx.x;
    if (b < G1) {
        int i = b * 256 + threadIdx.x;
        if (i >= n4) return;
        float4 v = ((const float4*)x)[i];
        ushort4 o;
        o.x = f2b(v.x); o.y = f2b(v.y); o.z = f2b(v.z); o.w = f2b(v.w);
        ((ushort4*)xb)[i] = o;
    } else {
        int id = (b - G1) * 256 + threadIdx.x;      // 0..65535
        int layer = id >> 15;
        int rem = id & 32767;
        int n = rem >> 8;
        int kk = rem & 255;
        const float* Wlp = layer ? W2l : W1l;
        const float* Wrp = layer ? W2r : W1r;
        float v = (kk < 128) ? Wlp[(size_t)kk * 128 + n]
                             : Wrp[(size_t)(kk - 128) * 128 + n];
        wt[(size_t)layer * 32768 + (size_t)n * 256 + kk] = f2b(v);
    }
}

// ---------------------------------------------------------------------------
// Feature-chunk-sharded mean aggregation (bf16 rows, fp32 accumulate).
// chunk c = blockIdx&7 covers features [c*16, c*16+16) (32B of each row) ->
// per-XCD input footprint 1.6MB, L2-resident. Output CHUNK-MAJOR:
// aggc[c][node][16] so writes stay XCD-local.
// Wave handles 4 nodes serially; per node: lane = es*2+half, 32 edges x 16B
// gathers in flight; xor-reduce over es; lanes es==0 store 2 x uint4.
// Fallback (deg > CAP): exact full-edge scan (never taken for this graph).
// ---------------------------------------------------------------------------
__global__ __launch_bounds__(256) void aggregate_c_kernel(
        const unsigned short* __restrict__ in, const int* __restrict__ cursor,
        const unsigned short* __restrict__ edge16, const int* __restrict__ ei,
        unsigned short* __restrict__ aggc, int E, int N) {
    int c    = blockIdx.x & 7;
    int nb   = blockIdx.x >> 3;
    int wave = threadIdx.x >> 6;
    int lane = threadIdx.x & 63;
    int es   = lane >> 1;          // edge slot 0..31
    int half = lane & 1;           // half-chunk (16B)
    int node0 = nb * 16 + wave * 4;

    for (int i = 0; i < 4; ++i) {
        int node = node0 + i;
        if (node >= N) break;
        int deg = cursor[node];
        float acc[8];
        #pragma unroll
        for (int t = 0; t < 8; ++t) acc[t] = 0.f;

        if (deg <= CAP) {
            const unsigned short* base = edge16 + (size_t)node * CAP;
            int idx = (lane < deg) ? (int)base[lane] : 0;   // coalesced preload
            for (int j = 0; j < deg; j += 32) {
                int e = j + es;
                int s = __shfl(idx, e & 63);                // all lanes execute
                if (e < deg) {
                    uint4 v = *(const uint4*)(in + (size_t)s * 128 + c * 16 + half * 8);
                    acc[0] += blo(v.x); acc[1] += bhi(v.x);
                    acc[2] += blo(v.y); acc[3] += bhi(v.y);
                    acc[4] += blo(v.z); acc[5] += bhi(v.z);
                    acc[6] += blo(v.w); acc[7] += bhi(v.w);
                }
            }
        } else {
            // exact fallback: scan the whole edge list for this node's chunk
            for (int j = 0; j < E; j += 32) {
                int e = j + es;
                bool act = (e < E) && (ei[E + e] == node);
                if (act) {
                    int s = ei[e];
                    if ((unsigned)s >= (unsigned)N) s = 0;
                    uint4 v = *(const uint4*)(in + (size_t)s * 128 + c * 16 + half * 8);
                    acc[0] += blo(v.x); acc[1] += bhi(v.x);
                    acc[2] += blo(v.y); acc[3] += bhi(v.y);
                    acc[4] += blo(v.z); acc[5] += bhi(v.z);
                    acc[6] += blo(v.w); acc[7] += bhi(v.w);
                }
            }
        }

        // reduce across edge slots (keep half separate: xor 2..32)
        #pragma unroll
        for (int d = 2; d <= 32; d <<= 1) {
            #pragma unroll
            for (int t = 0; t < 8; ++t) acc[t] += __shfl_xor(acc[t], d);
        }

        if (es == 0) {
            float inv = 1.0f / (float)(deg > 1 ? deg : 1);
            uint4 o;
            o.x = (unsigned)f2b(acc[0] * inv) | ((unsigned)f2b(acc[1] * inv) << 16);
            o.y = (unsigned)f2b(acc[2] * inv) | ((unsigned)f2b(acc[3] * inv) << 16);
            o.z = (unsigned)f2b(acc[4] * inv) | ((unsigned)f2b(acc[5] * inv) << 16);
            o.w = (unsigned)f2b(acc[6] * inv) | ((unsigned)f2b(acc[7] * inv) << 16);
            *(uint4*)(aggc + ((size_t)c * N + node) * 16 + half * 8) = o;
        }
    }
}

// ---------------------------------------------------------------------------
// MFMA GEMM: out[i,:] = (agg[i,:] || x[i,:]) @ Wt^T + bias (+ReLU)
// agg comes in CHUNK-MAJOR aggc[8][N][16]. M-tile 64 rows/block, 4 waves;
// wave w covers n in [32w, 32w+32).
// Layouts (m89/m120-verified): A[m=lane&15][k=quad*8+j],
// B[n=lane&15][k=quad*8+j], C/D col=lane&15, row=quad*4+reg.
// OUT_BF16=1 may alias Xrow (block-private rows staged to LDS before store).
// ---------------------------------------------------------------------------
template<int RELU, int OUT_BF16>
__global__ __launch_bounds__(256) void gemm_mfma_kernel(
        const unsigned short* __restrict__ aggc, const unsigned short* __restrict__ Xrow,
        const unsigned short* __restrict__ Wt, const float* __restrict__ bias,
        void* __restrict__ outp, int N) {
    constexpr int LDK = 264;
    __shared__ unsigned short sA[64 * LDK];
    int tid = threadIdx.x;
    int row0 = blockIdx.x * 64;

    // stage agg part (k=0..127) from chunk-major: 1024 uint4, 4/thread
    #pragma unroll
    for (int it = 0; it < 4; ++it) {
        int f = tid + it * 256;          // 0..1023
        int c = f >> 7;                  // chunk 0..7
        int rr = (f >> 1) & 63;          // row 0..63
        int h = f & 1;                   // half-chunk
        int row = row0 + rr; if (row >= N) row = N - 1;
        uint4 v = *(const uint4*)(aggc + ((size_t)c * N + row) * 16 + h * 8);
        *(uint4*)&sA[rr * LDK + c * 16 + h * 8] = v;
    }
    // stage x part (k=128..255) row-major: 1024 uint4, 4/thread
    #pragma unroll
    for (int it = 0; it < 4; ++it) {
        int f = tid + it * 256;
        int rr = f >> 4;                 // row 0..63
        int q = f & 15;                  // 16B chunk
        int row = row0 + rr; if (row >= N) row = N - 1;
        uint4 v = ((const uint4*)(Xrow + (size_t)row * 128))[q];
        *(uint4*)&sA[rr * LDK + 128 + q * 8] = v;
    }
    __syncthreads();

    int lane = tid & 63;
    int wave = tid >> 6;
    int quad = lane >> 4;
    int tm   = lane & 15;

    f32x4 acc[4][2];
    #pragma unroll
    for (int m = 0; m < 4; ++m)
        #pragma unroll
        for (int j = 0; j < 2; ++j)
            acc[m][j] = (f32x4){0.f, 0.f, 0.f, 0.f};

    const unsigned short* wb0 = Wt + (size_t)(wave * 32 + tm) * 256;

    #pragma unroll
    for (int ks = 0; ks < 8; ++ks) {
        int k0 = ks * 32 + quad * 8;
        bf16x8 a[4], b[2];
        #pragma unroll
        for (int m = 0; m < 4; ++m)
            a[m] = *(const bf16x8*)&sA[(m * 16 + tm) * LDK + k0];
        #pragma unroll
        for (int j = 0; j < 2; ++j)
            b[j] = *(const bf16x8*)(wb0 + (size_t)j * 16 * 256 + k0);
        #pragma unroll
        for (int m = 0; m < 4; ++m)
            #pragma unroll
            for (int j = 0; j < 2; ++j)
                acc[m][j] = __builtin_amdgcn_mfma_f32_16x16x32_bf16(a[m], b[j], acc[m][j], 0, 0, 0);
    }

    // epilogue: C/D col=lane&15 (-> ncol), row=quad*4+reg
    #pragma unroll
    for (int j = 0; j < 2; ++j) {
        int ncol = wave * 32 + j * 16 + tm;
        float bb = bias[ncol];
        #pragma unroll
        for (int m = 0; m < 4; ++m) {
            #pragma unroll
            for (int reg = 0; reg < 4; ++reg) {
                int row = row0 + m * 16 + quad * 4 + reg;
                if (row >= N) continue;
                float v = acc[m][j][reg] + bb;
                if (RELU) v = v > 0.f ? v : 0.f;
                if (OUT_BF16)
                    ((unsigned short*)outp)[(size_t)row * 128 + ncol] = f2b(v);
                else
                    ((float*)outp)[(size_t)row * 128 + ncol] = v;
            }
        }
    }
}

// ---------------------------------------------------------------------------
extern "C" void kernel_launch(void* const* d_in, const int* in_sizes, int n_in,
                              void* d_out, int out_size, void* d_ws, size_t ws_size,
                              hipStream_t stream) {
    const float* x   = (const float*)d_in[0];
    const int*   ei  = (const int*)d_in[1];     // int32 (harness converts int64)
    const float* W1l = (const float*)d_in[2];
    const float* b1  = (const float*)d_in[3];
    const float* W1r = (const float*)d_in[4];
    const float* W2l = (const float*)d_in[5];
    const float* b2  = (const float*)d_in[6];
    const float* W2r = (const float*)d_in[7];
    float* out = (float*)d_out;

    const int D = 128;
    const int N = in_sizes[0] / D;     // 50000
    const int E = in_sizes[1] / 2;     // 800000

    // workspace carve-out (512B aligned), ~33 MB total
    char* ws = (char*)d_ws;
    size_t off = 0;
    auto alloc = [&](size_t bytes) {
        size_t o = off;
        off = (off + bytes + 511) & ~(size_t)511;
        return (void*)(ws + o);
    };
    int*            cursor  = (int*)           alloc((size_t)N * 4);
    unsigned short* edge16  = (unsigned short*)alloc((size_t)N * CAP * 2);
    unsigned short* aggc    = (unsigned short*)alloc((size_t)N * D * 2);  // chunk-major [8][N][16]
    unsigned short* xb      = (unsigned short*)alloc((size_t)N * D * 2);
    unsigned short* wt      = (unsigned short*)alloc((size_t)2 * 128 * 256 * 2);
    unsigned short* h_bf = xb;         // gemm1 output aliases xb (block-private rows)
    (void)ws_size; (void)n_in; (void)out_size;

    // 1) slot fill, XCD-sharded (cursor doubles as degree)
    zero_kernel<<<(N + 255) / 256, 256, 0, stream>>>(cursor, N);
    {
        int G = 256;                       // chunks per shard; grid = 8*G
        int npg = (N + SH - 1) / SH;       // nodes per shard
        fill_shard_kernel<<<SH * G, 256, 0, stream>>>(ei, cursor, edge16, E, N, G, npg);
    }

    // 2) merged conversions: x -> xb ; weights -> wt
    int n4 = N * D / 4;
    int G1 = (n4 + 255) / 256;
    convert_kernel<<<G1 + 256, 256, 0, stream>>>(x, xb, n4, W1l, W1r, W2l, W2r, wt, G1);
    const unsigned short* wt1 = wt;
    const unsigned short* wt2 = wt + (size_t)128 * 256;

    int agg_grid  = 8 * ((N + 15) / 16);   // chunk = blockIdx&7 -> XCD&7
    int gemm_grid = (N + 63) / 64;

    // 3) layer 1 (h_bf aliases xb)
    aggregate_c_kernel<<<agg_grid, 256, 0, stream>>>(xb, cursor, edge16, ei, aggc, E, N);
    gemm_mfma_kernel<1, 1><<<gemm_grid, 256, 0, stream>>>(aggc, xb, wt1, b1, (void*)h_bf, N);

    // 4) layer 2
    aggregate_c_kernel<<<agg_grid, 256, 0, stream>>>(h_bf, cursor, edge16, ei, aggc, E, N);
    gemm_mfma_kernel<0, 0><<<gemm_grid, 256, 0, stream>>>(aggc, h_bf, wt2, b2, (void*)out, N);
}

// Round 9
// 234.914 us; speedup vs baseline: 2.1664x; 2.1664x over previous
//
#include <hip/hip_runtime.h>
#include <hip/hip_bf16.h>

typedef __attribute__((ext_vector_type(8))) short bf16x8;
typedef __attribute__((ext_vector_type(4))) float f32x4;

#define CAP 64   // fixed per-node edge slot capacity (deg>CAP -> exact fallback)
#define SH  8    // dst shards (== XCD count; blockIdx%8 ~ XCD heuristic)

// fp32 -> bf16 (round-to-nearest-even), bit pattern as ushort
static __device__ inline unsigned short f2b(float f) {
    unsigned u = __float_as_uint(f);
    unsigned r = (u + 0x7FFFu + ((u >> 16) & 1u)) >> 16;
    return (unsigned short)r;
}
// packed bf16 pair -> two fp32
static __device__ inline float blo(unsigned u) { return __uint_as_float(u << 16); }
static __device__ inline float bhi(unsigned u) { return __uint_as_float(u & 0xFFFF0000u); }
// pack 4 fp32 -> 4 OCP e4m3 bytes
static __device__ inline unsigned pk_fp8x4(float a, float b, float c, float d) {
    int v = __builtin_amdgcn_cvt_pk_fp8_f32(a, b, 0, false);
    v = __builtin_amdgcn_cvt_pk_fp8_f32(c, d, v, true);
    return (unsigned)v;
}

// ---------------------------------------------------------------------------
__global__ void zero_kernel(int* __restrict__ p, int n) {
    int i = blockIdx.x * blockDim.x + threadIdx.x;
    if (i < n) p[i] = 0;
}

// ---------------------------------------------------------------------------
// XCD-sharded slot fill. Shard s owns dst in [s*npg, (s+1)*npg); block b
// serves shard b&7 (lands on XCD b&7 -> each node's 128B slot line dirtied by
// one XCD -> single writeback). After this kernel cursor[d] == in-degree(d).
// edge_index int32: row 0 = src (ei[0..E)), row 1 = dst (ei[E..2E)).
// ---------------------------------------------------------------------------
__global__ __launch_bounds__(256) void fill_shard_kernel(
        const int* __restrict__ ei, int* __restrict__ cursor,
        unsigned short* __restrict__ edge16, int E, int N, int G, int npg) {
    int s = blockIdx.x & (SH - 1);
    int i = blockIdx.x >> 3;
    int d_lo = s * npg;
    int d_hi = d_lo + npg; if (d_hi > N) d_hi = N;
    int C = (E + G - 1) / G;
    int e0 = i * C;
    int e1 = e0 + C; if (e1 > E) e1 = E;
    for (int e = e0 + threadIdx.x; e < e1; e += 256) {
        int d = ei[E + e];
        if (d < d_lo || d >= d_hi) continue;
        int src = ei[e];
        if ((unsigned)src >= (unsigned)N) src = 0;   // defensive
        int pos = atomicAdd(&cursor[d], 1);
        if (pos < CAP) edge16[(size_t)d * CAP + pos] = (unsigned short)src;
    }
}

// ---------------------------------------------------------------------------
// Merged conversions (one launch):
// blocks [0, G1): x fp32 -> xb bf16 AND xf8 fp8-e4m3 (4 elems/thread)
// blocks [G1, G1+256): weights -> wt[layer][n][k] bf16 (k<128: Wl[k][n],
//   k>=128: Wr[k-128][n]); 2*128*256 elems.
// ---------------------------------------------------------------------------
__global__ __launch_bounds__(256) void convert_kernel(
        const float* __restrict__ x, unsigned short* __restrict__ xb,
        unsigned char* __restrict__ xf8, int n4,
        const float* __restrict__ W1l, const float* __restrict__ W1r,
        const float* __restrict__ W2l, const float* __restrict__ W2r,
        unsigned short* __restrict__ wt, int G1) {
    int b = blockIdx.x;
    if (b < G1) {
        int i = b * 256 + threadIdx.x;
        if (i >= n4) return;
        float4 v = ((const float4*)x)[i];
        ushort4 o;
        o.x = f2b(v.x); o.y = f2b(v.y); o.z = f2b(v.z); o.w = f2b(v.w);
        ((ushort4*)xb)[i] = o;
        ((unsigned*)xf8)[i] = pk_fp8x4(v.x, v.y, v.z, v.w);
    } else {
        int id = (b - G1) * 256 + threadIdx.x;      // 0..65535
        int layer = id >> 15;
        int rem = id & 32767;
        int n = rem >> 8;
        int kk = rem & 255;
        const float* Wlp = layer ? W2l : W1l;
        const float* Wrp = layer ? W2r : W1r;
        float v = (kk < 128) ? Wlp[(size_t)kk * 128 + n]
                             : Wrp[(size_t)(kk - 128) * 128 + n];
        wt[(size_t)layer * 32768 + (size_t)n * 256 + kk] = f2b(v);
    }
}

// ---------------------------------------------------------------------------
// bf16 rows -> fp8 shadow (for the layer-2 gather). 8 elems/thread.
// ---------------------------------------------------------------------------
__global__ __launch_bounds__(256) void b2f8_kernel(
        const unsigned short* __restrict__ hb, unsigned char* __restrict__ h8, int n8) {
    int i = blockIdx.x * blockDim.x + threadIdx.x;
    if (i >= n8) return;
    uint4 v = ((const uint4*)hb)[i];
    uint2 o;
    o.x = pk_fp8x4(blo(v.x), bhi(v.x), blo(v.y), bhi(v.y));
    o.y = pk_fp8x4(blo(v.z), bhi(v.z), blo(v.w), bhi(v.w));
    ((uint2*)h8)[i] = o;
}

// ---------------------------------------------------------------------------
// Mean aggregation over fp8 rows (fp32 accumulate, bf16 out).
// One wave per node (4 nodes / 256-block). fp8 row = 128B, so:
// lane = g*8+f : group g in [0,8) processes edge j+g; lane covers features
// f*16..f*16+15 via one uint4 (16B) gather -> 8 edges per load instruction,
// full row each. Gather bytes: 128B/edge (half of bf16).
// Cross-group shfl_xor (8,16,32) reduce; g==0 lanes write 16 bf16 (32B).
// Fallback (deg > CAP): exact full-edge scan (never taken for this graph).
// ---------------------------------------------------------------------------
__global__ __launch_bounds__(256) void aggregate_f8_kernel(
        const unsigned char* __restrict__ in8, const int* __restrict__ cursor,
        const unsigned short* __restrict__ edge16, const int* __restrict__ ei,
        unsigned short* __restrict__ agg, int E, int N) {
    int node = blockIdx.x * 4 + (threadIdx.x >> 6);
    if (node >= N) return;
    int lane = threadIdx.x & 63;
    int g = lane >> 3;          // edge group 0..7
    int f = lane & 7;           // 16B chunk = 16 features
    int deg = cursor[node];

    float acc[16];
    #pragma unroll
    for (int t = 0; t < 16; ++t) acc[t] = 0.f;

    if (deg <= CAP) {
        const unsigned short* base = edge16 + (size_t)node * CAP;
        int idx = (lane < deg) ? (int)base[lane] : 0;   // coalesced preload
        #pragma unroll 2
        for (int j = 0; j < deg; j += 8) {
            int e = j + g;
            int s = __shfl(idx, e & 63);
            if (e < deg) {
                uint4 v = *(const uint4*)(in8 + (size_t)s * 128 + f * 16);
                #pragma unroll
                for (int w = 0; w < 4; ++w) {
                    unsigned dw = (&v.x)[w];
                    acc[w * 4 + 0] += __builtin_amdgcn_cvt_f32_fp8(dw, 0);
                    acc[w * 4 + 1] += __builtin_amdgcn_cvt_f32_fp8(dw, 1);
                    acc[w * 4 + 2] += __builtin_amdgcn_cvt_f32_fp8(dw, 2);
                    acc[w * 4 + 3] += __builtin_amdgcn_cvt_f32_fp8(dw, 3);
                }
            }
        }
    } else {
        // exact fallback: scan the whole edge list for this node
        for (int j = 0; j < E; j += 8) {
            int e = j + g;
            bool act = (e < E) && (ei[E + e] == node);
            if (act) {
                int s = ei[e];
                if ((unsigned)s >= (unsigned)N) s = 0;
                uint4 v = *(const uint4*)(in8 + (size_t)s * 128 + f * 16);
                #pragma unroll
                for (int w = 0; w < 4; ++w) {
                    unsigned dw = (&v.x)[w];
                    acc[w * 4 + 0] += __builtin_amdgcn_cvt_f32_fp8(dw, 0);
                    acc[w * 4 + 1] += __builtin_amdgcn_cvt_f32_fp8(dw, 1);
                    acc[w * 4 + 2] += __builtin_amdgcn_cvt_f32_fp8(dw, 2);
                    acc[w * 4 + 3] += __builtin_amdgcn_cvt_f32_fp8(dw, 3);
                }
            }
        }
    }

    // reduce across the 8 edge-groups (xor lanes 8, 16, 32)
    #pragma unroll
    for (int d = 8; d <= 32; d <<= 1) {
        #pragma unroll
        for (int t = 0; t < 16; ++t) acc[t] += __shfl_xor(acc[t], d);
    }

    if (g == 0) {
        float inv = 1.0f / (float)(deg > 1 ? deg : 1);
        uint4 o0, o1;
        o0.x = (unsigned)f2b(acc[0] * inv)  | ((unsigned)f2b(acc[1] * inv)  << 16);
        o0.y = (unsigned)f2b(acc[2] * inv)  | ((unsigned)f2b(acc[3] * inv)  << 16);
        o0.z = (unsigned)f2b(acc[4] * inv)  | ((unsigned)f2b(acc[5] * inv)  << 16);
        o0.w = (unsigned)f2b(acc[6] * inv)  | ((unsigned)f2b(acc[7] * inv)  << 16);
        o1.x = (unsigned)f2b(acc[8] * inv)  | ((unsigned)f2b(acc[9] * inv)  << 16);
        o1.y = (unsigned)f2b(acc[10] * inv) | ((unsigned)f2b(acc[11] * inv) << 16);
        o1.z = (unsigned)f2b(acc[12] * inv) | ((unsigned)f2b(acc[13] * inv) << 16);
        o1.w = (unsigned)f2b(acc[14] * inv) | ((unsigned)f2b(acc[15] * inv) << 16);
        unsigned short* dst = agg + (size_t)node * 128 + f * 16;
        *(uint4*)dst = o0;
        *(uint4*)(dst + 8) = o1;
    }
}

// ---------------------------------------------------------------------------
// MFMA GEMM: out[i,:] = (agg_bf[i,:] || xrow_bf[i,:]) @ Wt^T + bias (+ReLU)
// M-tile 64 rows/block, 4 waves; wave w covers n in [32w, 32w+32).
// Layouts (m89/m120-verified): A[m=lane&15][k=quad*8+j],
// B[n=lane&15][k=quad*8+j], C/D col=lane&15, row=quad*4+reg.
// OUT_BF16=1 may alias Xrow (block-private rows staged to LDS before store).
// ---------------------------------------------------------------------------
template<int RELU, int OUT_BF16>
__global__ __launch_bounds__(256) void gemm_mfma_kernel(
        const unsigned short* __restrict__ Arow, const unsigned short* __restrict__ Xrow,
        const unsigned short* __restrict__ Wt, const float* __restrict__ bias,
        void* __restrict__ outp, int n) {
    constexpr int LDK = 264;
    __shared__ unsigned short sA[64 * LDK];
    int tid = threadIdx.x;
    int row0 = blockIdx.x * 64;

    // stage 64 rows x 256 bf16 = 2048 x 16B chunks, 8/thread
    #pragma unroll
    for (int it = 0; it < 8; ++it) {
        int c = tid + it * 256;
        int r = c >> 5;              // row 0..63
        int q = c & 31;              // 16B chunk in row
        int row = row0 + r; if (row >= n) row = n - 1;
        uint4 v = (q < 16) ? ((const uint4*)(Arow + (size_t)row * 128))[q]
                           : ((const uint4*)(Xrow + (size_t)row * 128))[q - 16];
        *(uint4*)&sA[r * LDK + q * 8] = v;
    }
    __syncthreads();

    int lane = tid & 63;
    int wave = tid >> 6;
    int quad = lane >> 4;
    int tm   = lane & 15;

    f32x4 acc[4][2];
    #pragma unroll
    for (int m = 0; m < 4; ++m)
        #pragma unroll
        for (int j = 0; j < 2; ++j)
            acc[m][j] = (f32x4){0.f, 0.f, 0.f, 0.f};

    const unsigned short* wb0 = Wt + (size_t)(wave * 32 + tm) * 256;

    #pragma unroll
    for (int ks = 0; ks < 8; ++ks) {
        int k0 = ks * 32 + quad * 8;
        bf16x8 a[4], b[2];
        #pragma unroll
        for (int m = 0; m < 4; ++m)
            a[m] = *(const bf16x8*)&sA[(m * 16 + tm) * LDK + k0];
        #pragma unroll
        for (int j = 0; j < 2; ++j)
            b[j] = *(const bf16x8*)(wb0 + (size_t)j * 16 * 256 + k0);
        #pragma unroll
        for (int m = 0; m < 4; ++m)
            #pragma unroll
            for (int j = 0; j < 2; ++j)
                acc[m][j] = __builtin_amdgcn_mfma_f32_16x16x32_bf16(a[m], b[j], acc[m][j], 0, 0, 0);
    }

    // epilogue: C/D col=lane&15 (-> ncol), row=quad*4+reg
    #pragma unroll
    for (int j = 0; j < 2; ++j) {
        int ncol = wave * 32 + j * 16 + tm;
        float bb = bias[ncol];
        #pragma unroll
        for (int m = 0; m < 4; ++m) {
            #pragma unroll
            for (int reg = 0; reg < 4; ++reg) {
                int row = row0 + m * 16 + quad * 4 + reg;
                if (row >= n) continue;
                float v = acc[m][j][reg] + bb;
                if (RELU) v = v > 0.f ? v : 0.f;
                if (OUT_BF16)
                    ((unsigned short*)outp)[(size_t)row * 128 + ncol] = f2b(v);
                else
                    ((float*)outp)[(size_t)row * 128 + ncol] = v;
            }
        }
    }
}

// ---------------------------------------------------------------------------
extern "C" void kernel_launch(void* const* d_in, const int* in_sizes, int n_in,
                              void* d_out, int out_size, void* d_ws, size_t ws_size,
                              hipStream_t stream) {
    const float* x   = (const float*)d_in[0];
    const int*   ei  = (const int*)d_in[1];     // int32 (harness converts int64)
    const float* W1l = (const float*)d_in[2];
    const float* b1  = (const float*)d_in[3];
    const float* W1r = (const float*)d_in[4];
    const float* W2l = (const float*)d_in[5];
    const float* b2  = (const float*)d_in[6];
    const float* W2r = (const float*)d_in[7];
    float* out = (float*)d_out;

    const int D = 128;
    const int N = in_sizes[0] / D;     // 50000
    const int E = in_sizes[1] / 2;     // 800000

    // workspace carve-out (512B aligned), ~39 MB total
    char* ws = (char*)d_ws;
    size_t off = 0;
    auto alloc = [&](size_t bytes) {
        size_t o = off;
        off = (off + bytes + 511) & ~(size_t)511;
        return (void*)(ws + o);
    };
    int*            cursor  = (int*)           alloc((size_t)N * 4);
    unsigned short* edge16  = (unsigned short*)alloc((size_t)N * CAP * 2);
    unsigned short* agg_bf  = (unsigned short*)alloc((size_t)N * D * 2);
    unsigned short* xb      = (unsigned short*)alloc((size_t)N * D * 2);
    unsigned char*  xf8     = (unsigned char*) alloc((size_t)N * D);
    unsigned short* wt      = (unsigned short*)alloc((size_t)2 * 128 * 256 * 2);
    unsigned short* h_bf = xb;          // gemm1 output aliases xb (block-private rows)
    unsigned char*  h_f8 = xf8;         // fp8 shadow of h aliases xf8 (dead after agg1)
    (void)ws_size; (void)n_in; (void)out_size;

    // 1) slot fill, XCD-sharded (cursor doubles as degree)
    zero_kernel<<<(N + 255) / 256, 256, 0, stream>>>(cursor, N);
    {
        int G = 256;                       // chunks per shard; grid = 8*G
        int npg = (N + SH - 1) / SH;       // nodes per shard
        fill_shard_kernel<<<SH * G, 256, 0, stream>>>(ei, cursor, edge16, E, N, G, npg);
    }

    // 2) merged conversions: x -> xb (bf16) + xf8 (fp8) ; weights -> wt
    int n4 = N * D / 4;
    int G1 = (n4 + 255) / 256;
    convert_kernel<<<G1 + 256, 256, 0, stream>>>(x, xb, xf8, n4, W1l, W1r, W2l, W2r, wt, G1);
    const unsigned short* wt1 = wt;
    const unsigned short* wt2 = wt + (size_t)128 * 256;

    int agg_grid  = (N + 3) / 4;
    int gemm_grid = (N + 63) / 64;
    int n8 = N * D / 8;

    // 3) layer 1 (h_bf aliases xb — block-private rows in gemm)
    aggregate_f8_kernel<<<agg_grid, 256, 0, stream>>>(xf8, cursor, edge16, ei, agg_bf, E, N);
    gemm_mfma_kernel<1, 1><<<gemm_grid, 256, 0, stream>>>(agg_bf, xb, wt1, b1, (void*)h_bf, N);

    // 4) fp8 shadow of h, then layer 2
    b2f8_kernel<<<(n8 + 255) / 256, 256, 0, stream>>>(h_bf, h_f8, n8);
    aggregate_f8_kernel<<<agg_grid, 256, 0, stream>>>(h_f8, cursor, edge16, ei, agg_bf, E, N);
    gemm_mfma_kernel<0, 0><<<gemm_grid, 256, 0, stream>>>(agg_bf, h_bf, wt2, b2, (void*)out, N);
}